// Round 13
// baseline (205.064 us; speedup 1.0000x reference)
//
#include <hip/hip_runtime.h>
#include <hip/hip_bf16.h>

typedef __hip_bfloat16 bf16;
using f4 = __attribute__((ext_vector_type(4))) float;
using s8 = __attribute__((ext_vector_type(8))) short;
using s4 = __attribute__((ext_vector_type(4))) short;

__device__ __forceinline__ void storeOut(float* p, float v) { *p = v; }
__device__ __forceinline__ void storeOut(bf16* p, float v) { *p = __float2bfloat16(v); }
__device__ __forceinline__ short bfs(float x) { return __builtin_bit_cast(short, __float2bfloat16(x)); }

// async 16-byte global->LDS DMA; lds base must be wave-uniform (HW scatters lane*16)
__device__ __forceinline__ void gl16(const void* g, void* l) {
    __builtin_amdgcn_global_load_lds(
        (const __attribute__((address_space(1))) unsigned int*)g,
        (__attribute__((address_space(3))) unsigned int*)l, 16, 0, 0);
}

constexpr int B_ = 4, T_ = 1024, M_ = 256, C_ = 512, H_ = 8, HD_ = 64, C3_ = 1536;

#define MFMA16(a, b, c) __builtin_amdgcn_mfma_f32_16x16x32_bf16((a), (b), (c), 0, 0, 0)

// ---------------- prep: 5 weight transposes (fp32 KxN -> bf16 NxK) + 2 converts ----------------
__global__ __launch_bounds__(256) void prep_kernel(
    const float* __restrict__ Wqkv_x, const float* __restrict__ Wqkv_y,
    const float* __restrict__ Wgs, const float* __restrict__ Wgc, const float* __restrict__ Wp,
    const float* __restrict__ x, const float* __restrict__ y,
    bf16* __restrict__ WT_x, bf16* __restrict__ WT_y, bf16* __restrict__ WT_gs,
    bf16* __restrict__ WT_gc, bf16* __restrict__ WT_p,
    bf16* __restrict__ x_bf, bf16* __restrict__ y_bf)
{
    __shared__ float Ls[64][65];
    const int tid = threadIdx.x;
    const int bid = blockIdx.x;
    if (bid < 576) {
        const float* W; bf16* WT; int N, t;
        if (bid < 192)      { W = Wqkv_x; WT = WT_x;  N = C3_; t = bid; }
        else if (bid < 384) { W = Wqkv_y; WT = WT_y;  N = C3_; t = bid - 192; }
        else if (bid < 448) { W = Wgs;    WT = WT_gs; N = C_;  t = bid - 384; }
        else if (bid < 512) { W = Wgc;    WT = WT_gc; N = C_;  t = bid - 448; }
        else                { W = Wp;     WT = WT_p;  N = C_;  t = bid - 512; }
        const int K = C_;
        const int tw = N >> 6;
        const int n0 = (t % tw) * 64, k0 = (t / tw) * 64;
        for (int i = tid; i < 1024; i += 256) {
            int kr = i >> 4, ng = i & 15;
            float4 v = *(const float4*)&W[(size_t)(k0 + kr) * N + n0 + ng * 4];
            Ls[ng * 4 + 0][kr] = v.x; Ls[ng * 4 + 1][kr] = v.y;
            Ls[ng * 4 + 2][kr] = v.z; Ls[ng * 4 + 3][kr] = v.w;
        }
        __syncthreads();
        for (int i = tid; i < 512; i += 256) {
            int n = i >> 3, kg = i & 7;
            s8 r;
            #pragma unroll
            for (int j = 0; j < 8; ++j) r[j] = bfs(Ls[n][kg * 8 + j]);
            *(s8*)&WT[(size_t)(n0 + n) * K + k0 + kg * 8] = r;
        }
    } else if (bid < 1600) {
        int i = (bid - 576) * 2048 + tid * 8;
        s8 r;
        #pragma unroll
        for (int j = 0; j < 8; ++j) r[j] = bfs(x[i + j]);
        *(s8*)&x_bf[i] = r;
    } else {
        int i = (bid - 1600) * 2048 + tid * 8;
        s8 r;
        #pragma unroll
        for (int j = 0; j < 8; ++j) r[j] = bfs(y[i + j]);
        *(s8*)&y_bf[i] = r;
    }
}

// ---------------- shared GEMM body (128x64 tile) — gl16 staging, XOR-swizzled LDS ----------------
template <typename OT>
__device__ __forceinline__ void gemm_body(
    short* __restrict__ Asb, short* __restrict__ Bsb,
    const bf16* __restrict__ A, const bf16* __restrict__ WT, const float* __restrict__ bias,
    OT* __restrict__ Cmat, int N, int K, int m0, int n0)
{
    const int tid = threadIdx.x;
    const int wave = tid >> 6, lane = tid & 63;
    const int quad = lane >> 4, l16 = lane & 15;
    const int sx = l16 & 7;
    const int lrow = lane >> 3;
    const int lcol = ((lane & 7) ^ lrow) * 8;
    f4 acc[2][4];
    #pragma unroll
    for (int mt = 0; mt < 2; ++mt)
        #pragma unroll
        for (int nt = 0; nt < 4; ++nt) acc[mt][nt] = (f4)0.f;

    for (int k0 = 0; k0 < K; k0 += 64) {
        #pragma unroll
        for (int i = 0; i < 4; ++i) {
            int c = wave * 4 + i;
            gl16(&A[(size_t)(m0 + c * 8 + lrow) * K + k0 + lcol], &Asb[c * 512]);
        }
        #pragma unroll
        for (int i = 0; i < 2; ++i) {
            int c = wave * 2 + i;
            gl16(&WT[(size_t)(n0 + c * 8 + lrow) * K + k0 + lcol], &Bsb[c * 512]);
        }
        __syncthreads();
        #pragma unroll
        for (int ks = 0; ks < 2; ++ks) {
            const int g8 = ((ks * 4 + quad) ^ sx) * 8;
            s8 a0 = *(const s8*)&Asb[(wave * 32 + l16) * 64 + g8];
            s8 a1 = *(const s8*)&Asb[(wave * 32 + 16 + l16) * 64 + g8];
            #pragma unroll
            for (int nt = 0; nt < 4; ++nt) {
                s8 bv = *(const s8*)&Bsb[(nt * 16 + l16) * 64 + g8];
                acc[0][nt] = MFMA16(a0, bv, acc[0][nt]);
                acc[1][nt] = MFMA16(a1, bv, acc[1][nt]);
            }
        }
        __syncthreads();
    }
    #pragma unroll
    for (int mt = 0; mt < 2; ++mt)
        #pragma unroll
        for (int nt = 0; nt < 4; ++nt) {
            int col = n0 + nt * 16 + l16;
            float bb = bias[col];
            #pragma unroll
            for (int reg = 0; reg < 4; ++reg) {
                int row = m0 + wave * 32 + mt * 16 + quad * 4 + reg;
                storeOut(&Cmat[(size_t)row * N + col], acc[mt][nt][reg] + bb);
            }
        }
}

template <typename OT>
__global__ __launch_bounds__(256) void gemm_staged_kernel(
    const bf16* __restrict__ A, const bf16* __restrict__ WT, const float* __restrict__ bias,
    OT* __restrict__ Cmat, int N, int K)
{
    __shared__ short Asb[128 * 64];
    __shared__ short Bsb[64 * 64];
    gemm_body<OT>(Asb, Bsb, A, WT, bias, Cmat, N, K, blockIdx.x * 128, blockIdx.y * 64);
}

// ---------------- 128x128-tile GEMM body (qkv only): 32 MFMA per barrier pair,
// halved B-panel re-reads. Same gl16 + XOR-swizzle scheme; acc[2][8]. ----------------
__device__ __forceinline__ void gemm_body128(
    short* __restrict__ Asb, short* __restrict__ Bsb,
    const bf16* __restrict__ A, const bf16* __restrict__ WT, const float* __restrict__ bias,
    bf16* __restrict__ Cmat, int N, int K, int m0, int n0)
{
    const int tid = threadIdx.x;
    const int wave = tid >> 6, lane = tid & 63;
    const int quad = lane >> 4, l16 = lane & 15;
    const int sx = l16 & 7;
    const int lrow = lane >> 3;
    const int lcol = ((lane & 7) ^ lrow) * 8;
    f4 acc[2][8];
    #pragma unroll
    for (int mt = 0; mt < 2; ++mt)
        #pragma unroll
        for (int nt = 0; nt < 8; ++nt) acc[mt][nt] = (f4)0.f;

    for (int k0 = 0; k0 < K; k0 += 64) {
        #pragma unroll
        for (int i = 0; i < 4; ++i) {
            int c = wave * 4 + i;
            gl16(&A[(size_t)(m0 + c * 8 + lrow) * K + k0 + lcol], &Asb[c * 512]);
        }
        #pragma unroll
        for (int i = 0; i < 4; ++i) {
            int c = wave * 4 + i;
            gl16(&WT[(size_t)(n0 + c * 8 + lrow) * K + k0 + lcol], &Bsb[c * 512]);
        }
        __syncthreads();
        #pragma unroll
        for (int ks = 0; ks < 2; ++ks) {
            const int g8 = ((ks * 4 + quad) ^ sx) * 8;
            s8 a0 = *(const s8*)&Asb[(wave * 32 + l16) * 64 + g8];
            s8 a1 = *(const s8*)&Asb[(wave * 32 + 16 + l16) * 64 + g8];
            #pragma unroll
            for (int nt = 0; nt < 8; ++nt) {
                s8 bv = *(const s8*)&Bsb[(nt * 16 + l16) * 64 + g8];
                acc[0][nt] = MFMA16(a0, bv, acc[0][nt]);
                acc[1][nt] = MFMA16(a1, bv, acc[1][nt]);
            }
        }
        __syncthreads();
    }
    #pragma unroll
    for (int mt = 0; mt < 2; ++mt)
        #pragma unroll
        for (int nt = 0; nt < 8; ++nt) {
            int col = n0 + nt * 16 + l16;
            float bb = bias[col];
            #pragma unroll
            for (int reg = 0; reg < 4; ++reg) {
                int row = m0 + wave * 32 + mt * 16 + quad * 4 + reg;
                storeOut(&Cmat[(size_t)row * N + col], acc[mt][nt][reg] + bb);
            }
        }
}

// ---------------- merged QKV x + y projection, 128x128 tiles (480 blocks, XCD swizzle) ----------------
__global__ __launch_bounds__(256) void qkv_gemm_kernel(
    const bf16* __restrict__ x_bf, const bf16* __restrict__ y_bf,
    const bf16* __restrict__ WTx, const bf16* __restrict__ WTy,
    const float* __restrict__ bqx, const float* __restrict__ bqy,
    bf16* __restrict__ qkv_x, bf16* __restrict__ qkv_y)
{
    __shared__ short Asb[128 * 64];
    __shared__ short Bsb[128 * 64];
    const int t = (blockIdx.x & 7) * 60 + (blockIdx.x >> 3);   // XCD swizzle (480 % 8 == 0)
    if (t < 384) {
        gemm_body128(Asb, Bsb, x_bf, WTx, bqx, qkv_x, C3_, C_, (t & 31) * 128, (t >> 5) * 128);
    } else {
        const int u = t - 384;
        gemm_body128(Asb, Bsb, y_bf, WTy, bqy, qkv_y, C3_, C_, (u & 7) * 128, (u >> 3) * 128);
    }
}

// ---------------- catt3rv: inline catt1/catt2 + logits + row softmax + V transposes ----------------
__global__ __launch_bounds__(256) void catt3rv_kernel(
    const bf16* __restrict__ qkv_x, const bf16* __restrict__ qkv_y,
    const float* __restrict__ w4x, const float* __restrict__ w4y,
    const float* __restrict__ w4xy,
    bf16* __restrict__ x2y, float* __restrict__ rowsum_, float* __restrict__ psum,
    bf16* __restrict__ vTx, bf16* __restrict__ vTy)
{
    __shared__ float redc[4][256];
    __shared__ float c1s[64];
    __shared__ float c2s[256];
    __shared__ short Ls[64][68];
    const int tid = threadIdx.x;
    int bid = blockIdx.x;

    if (bid >= 512) {
        int vb = bid - 512;
        const bf16* qkv; bf16* vT; int Nrows, bh, t0;
        if (vb < 512) { qkv = qkv_x; vT = vTx; Nrows = T_; bh = vb >> 4; t0 = (vb & 15) * 64; }
        else { vb -= 512; qkv = qkv_y; vT = vTy; Nrows = M_; bh = vb >> 2; t0 = (vb & 3) * 64; }
        const int b = bh >> 3, h = bh & 7;
        for (int i = tid; i < 4096; i += 256) {
            int tl = i >> 6, d = i & 63;
            Ls[d][tl] = __builtin_bit_cast(short,
                qkv[(size_t)(b * Nrows + t0 + tl) * C3_ + 2 * C_ + h * HD_ + d]);
        }
        __syncthreads();
        for (int i = tid; i < 4096; i += 256) {
            int d = i >> 6, tl = i & 63;
            vT[((size_t)bh * 64 + d) * Nrows + t0 + tl] = __builtin_bit_cast(bf16, Ls[d][tl]);
        }
        return;
    }

    const int wave = tid >> 6, lane = tid & 63;
    const int quad = lane >> 4, l16 = lane & 15;
    const int bh = bid >> 4, b = bh >> 3, h = bh & 7;
    const int t0 = (bid & 15) * 64;

    {
        const bf16* row = qkv_y + (size_t)(b * M_ + tid) * C3_ + h * HD_;
        const float* w = w4y + h * HD_;
        float s = 0.f;
        #pragma unroll
        for (int d = 0; d < HD_; ++d) s = fmaf(__bfloat162float(row[d]), w[d], s);
        c2s[tid] = s;
    }
    if (tid < 64) {
        const bf16* row = qkv_x + (size_t)(b * T_ + t0 + tid) * C3_ + h * HD_;
        const float* w = w4x + h * HD_;
        float s = 0.f;
        #pragma unroll
        for (int d = 0; d < HD_; ++d) s = fmaf(__bfloat162float(row[d]), w[d], s);
        c1s[tid] = s;
    }

    f4 sc[4][4];
    #pragma unroll
    for (int mt = 0; mt < 4; ++mt)
        #pragma unroll
        for (int nt = 0; nt < 4; ++nt) sc[mt][nt] = (f4)0.f;

    const bf16* ap = qkv_x + (size_t)(b * T_ + t0 + wave * 16 + l16) * C3_ + h * HD_ + quad * 8;
    s8 a0r = *(const s8*)ap;
    s8 a1r = *(const s8*)(ap + 32);
    const float* wx = w4xy + h * HD_ + quad * 8;
    s8 a0, a1;
    #pragma unroll
    for (int j = 0; j < 8; ++j) {
        a0[j] = bfs(__bfloat162float(__builtin_bit_cast(bf16, a0r[j])) * wx[j]);
        a1[j] = bfs(__bfloat162float(__builtin_bit_cast(bf16, a1r[j])) * wx[j + 32]);
    }
    const bf16* bp = qkv_y + (size_t)(b * M_ + l16) * C3_ + C_ + h * HD_ + quad * 8;
    #pragma unroll
    for (int mt = 0; mt < 4; ++mt)
        #pragma unroll
        for (int nt = 0; nt < 4; ++nt) {
            const bf16* bq = bp + (size_t)(mt * 64 + nt * 16) * C3_;
            sc[mt][nt] = MFMA16(a0, *(const s8*)bq, sc[mt][nt]);
            sc[mt][nt] = MFMA16(a1, *(const s8*)(bq + 32), sc[mt][nt]);
        }
    __syncthreads();   // c1s/c2s ready

    float c1[4];
    #pragma unroll
    for (int reg = 0; reg < 4; ++reg)
        c1[reg] = c1s[wave * 16 + quad * 4 + reg];
    #pragma unroll
    for (int mt = 0; mt < 4; ++mt)
        #pragma unroll
        for (int nt = 0; nt < 4; ++nt) {
            float c2 = c2s[mt * 64 + nt * 16 + l16];
            #pragma unroll
            for (int reg = 0; reg < 4; ++reg)
                sc[mt][nt][reg] = __expf(sc[mt][nt][reg] * 0.125f + c1[reg] + c2);
        }

    #pragma unroll
    for (int reg = 0; reg < 4; ++reg) {
        float rs = 0.f;
        #pragma unroll
        for (int mt = 0; mt < 4; ++mt)
            #pragma unroll
            for (int nt = 0; nt < 4; ++nt) rs += sc[mt][nt][reg];
        rs += __shfl_xor(rs, 1); rs += __shfl_xor(rs, 2);
        rs += __shfl_xor(rs, 4); rs += __shfl_xor(rs, 8);
        const int t = t0 + wave * 16 + quad * 4 + reg;
        if (l16 == 0) rowsum_[bh * T_ + t] = rs;
        const float ri = 1.f / rs;
        #pragma unroll
        for (int mt = 0; mt < 4; ++mt)
            #pragma unroll
            for (int nt = 0; nt < 4; ++nt)
                x2y[((size_t)bh * T_ + t) * M_ + mt * 64 + nt * 16 + l16] =
                    __float2bfloat16(sc[mt][nt][reg] * ri);
    }

    #pragma unroll
    for (int mt = 0; mt < 4; ++mt)
        #pragma unroll
        for (int nt = 0; nt < 4; ++nt) {
            float es = sc[mt][nt][0] + sc[mt][nt][1] + sc[mt][nt][2] + sc[mt][nt][3];
            es += __shfl_xor(es, 16);
            es += __shfl_xor(es, 32);
            if (quad == 0) redc[wave][mt * 64 + nt * 16 + l16] = es;
        }
    __syncthreads();
    psum[((size_t)bh * 16 + (bid & 15)) * M_ + tid] =
        redc[0][tid] + redc[1][tid] + redc[2][tid] + redc[3][tid];
}

// ---------------- flash15: proven (unchanged) ----------------
__global__ __launch_bounds__(512) void flash15_kernel(
    const bf16* __restrict__ x2y, const float* __restrict__ rowsum_,
    const float* __restrict__ psum_,
    const bf16* __restrict__ vTx, const bf16* __restrict__ vTy,
    const bf16* __restrict__ qkv_x, const float* __restrict__ x,
    bf16* __restrict__ cval_bf, bf16* __restrict__ sval_bf)
{
    __shared__ short Kc[64][264];
    __shared__ short Ksf[64][72];
    __shared__ short Vb[64][72];
    __shared__ short Ps[8][16][68];
    __shared__ float cinv[256];
    const int tid = threadIdx.x;
    const int wave = tid >> 6, lane = tid & 63;
    const int quad = lane >> 4, l16 = lane & 15;
    const int bh = blockIdx.x, b = bh >> 3, h = bh & 7;
    const int p = blockIdx.y;
    const int jt = (wave < 4) ? p : (15 - p);
    const int rb = jt * 64 + (wave & 3) * 16;
    const int nst = 16 - p;

    if (tid < 256) {
        float s = 0.f;
        #pragma unroll
        for (int ch = 0; ch < 16; ++ch) s += psum_[(size_t)(bh * 16 + ch) * M_ + tid];
        cinv[tid] = 1.f / s;
    }

    s8 qc[8], qs[2];
    {
        const bf16* qp = x2y + (size_t)(bh * T_ + rb + l16) * M_ + quad * 8;
        #pragma unroll
        for (int f = 0; f < 8; ++f) qc[f] = *(const s8*)(qp + f * 32);
        const bf16* qsp = qkv_x + (size_t)(b * T_ + rb + l16) * C3_ + h * HD_ + quad * 8;
        qs[0] = *(const s8*)qsp;
        qs[1] = *(const s8*)(qsp + 32);
    }

    #pragma unroll
    for (int tl = 0; tl < 4; ++tl) {
        int g = tid + tl * 512, row = g >> 5, grp = g & 31;
        *(s8*)&Kc[row][grp * 8] = *(const s8*)&x2y[(size_t)(bh * T_ + row) * M_ + grp * 8];
    }
    {
        int row = tid >> 3, grp = tid & 7;
        *(s8*)&Ksf[row][grp * 8] =
            *(const s8*)&qkv_x[(size_t)(b * T_ + row) * C3_ + C_ + h * HD_ + grp * 8];
        *(s8*)&Vb[row][grp * 8] = *(const s8*)&vTx[(size_t)(bh * 64 + row) * T_ + grp * 8];
    }
    __syncthreads();

    f4 ocv[4];
    #pragma unroll
    for (int dt = 0; dt < 4; ++dt) ocv[dt] = (f4)0.f;
    {
        const bf16* vb = vTy + (size_t)(bh * 64 + l16) * M_ + quad * 8;
        #pragma unroll
        for (int f = 0; f < 8; ++f)
            #pragma unroll
            for (int dt = 0; dt < 4; ++dt) {
                s8 bv = *(const s8*)(vb + (size_t)dt * 16 * M_ + f * 32);
                ocv[dt] = MFMA16(qc[f], bv, ocv[dt]);
            }
    }

    #pragma unroll
    for (int f = 0; f < 8; ++f) {
        const float* cp = &cinv[f * 32 + quad * 8];
        s8 q = qc[f], r;
        #pragma unroll
        for (int j = 0; j < 8; ++j)
            r[j] = bfs(__bfloat162float(__builtin_bit_cast(bf16, q[j])) * cp[j]);
        qc[f] = r;
    }

    f4 oc[4], os_[4];
    float lc[4] = {0.f, 0.f, 0.f, 0.f}, ls_[4] = {0.f, 0.f, 0.f, 0.f};
    #pragma unroll
    for (int dt = 0; dt < 4; ++dt) { oc[dt] = (f4)0.f; os_[dt] = (f4)0.f; }

    for (int st = 0; st < nst; ++st) {
        const int s0 = st * 64;
        const bool pf = (st + 1) < nst;
        s8 kcp[4], ksp, vp;
        if (pf) {
            const int sn = s0 + 64;
            #pragma unroll
            for (int tl = 0; tl < 4; ++tl) {
                int g = tid + tl * 512, row = g >> 5, grp = g & 31;
                kcp[tl] = *(const s8*)&x2y[(size_t)(bh * T_ + sn + row) * M_ + grp * 8];
            }
            int row = tid >> 3, grp = tid & 7;
            ksp = *(const s8*)&qkv_x[(size_t)(b * T_ + sn + row) * C3_ + C_ + h * HD_ + grp * 8];
            vp = *(const s8*)&vTx[(size_t)(bh * 64 + row) * T_ + sn + grp * 8];
        }
        if (st <= jt) {
            float rsS[4];
            #pragma unroll
            for (int nt = 0; nt < 4; ++nt)
                rsS[nt] = rowsum_[bh * T_ + s0 + nt * 16 + l16] * 0.0625f;
            f4 sc[4];
            #pragma unroll
            for (int nt = 0; nt < 4; ++nt) sc[nt] = (f4)0.f;
            #pragma unroll
            for (int f = 0; f < 8; ++f)
                #pragma unroll
                for (int nt = 0; nt < 4; ++nt) {
                    s8 bv = *(const s8*)&Kc[nt * 16 + l16][f * 32 + quad * 8];
                    sc[nt] = MFMA16(qc[f], bv, sc[nt]);
                }
            f4 ss[4];
            #pragma unroll
            for (int nt = 0; nt < 4; ++nt) ss[nt] = (f4)0.f;
            #pragma unroll
            for (int f = 0; f < 2; ++f)
                #pragma unroll
                for (int nt = 0; nt < 4; ++nt) {
                    s8 bv = *(const s8*)&Ksf[nt * 16 + l16][f * 32 + quad * 8];
                    ss[nt] = MFMA16(qs[f], bv, ss[nt]);
                }
            #pragma unroll
            for (int reg = 0; reg < 4; ++reg) {
                const int t_g = rb + quad * 4 + reg;
                #pragma unroll
                for (int nt = 0; nt < 4; ++nt) {
                    float pv = (s0 + nt * 16 + l16 <= t_g) ? __expf(sc[nt][reg] * rsS[nt]) : 0.f;
                    lc[reg] += pv;
                    Ps[wave][quad * 4 + reg][nt * 16 + l16] = bfs(pv);
                }
            }
            #pragma unroll
            for (int ks = 0; ks < 2; ++ks) {
                const short* pp = &Ps[wave][l16][ks * 32 + quad * 8];
                s4 alo = *(const s4*)pp;
                s4 ahi = *(const s4*)(pp + 4);
                s8 a;
                a[0] = alo[0]; a[1] = alo[1]; a[2] = alo[2]; a[3] = alo[3];
                a[4] = ahi[0]; a[5] = ahi[1]; a[6] = ahi[2]; a[7] = ahi[3];
                #pragma unroll
                for (int dt = 0; dt < 4; ++dt) {
                    s8 bv = *(const s8*)&Vb[dt * 16 + l16][ks * 32 + quad * 8];
                    oc[dt] = MFMA16(a, bv, oc[dt]);
                }
            }
            #pragma unroll
            for (int reg = 0; reg < 4; ++reg) {
                const int t_g = rb + quad * 4 + reg;
                #pragma unroll
                for (int nt = 0; nt < 4; ++nt) {
                    float pv = (s0 + nt * 16 + l16 <= t_g) ? __expf(ss[nt][reg] * 0.125f) : 0.f;
                    ls_[reg] += pv;
                    Ps[wave][quad * 4 + reg][nt * 16 + l16] = bfs(pv);
                }
            }
            #pragma unroll
            for (int ks = 0; ks < 2; ++ks) {
                const short* pp = &Ps[wave][l16][ks * 32 + quad * 8];
                s4 alo = *(const s4*)pp;
                s4 ahi = *(const s4*)(pp + 4);
                s8 a;
                a[0] = alo[0]; a[1] = alo[1]; a[2] = alo[2]; a[3] = alo[3];
                a[4] = ahi[0]; a[5] = ahi[1]; a[6] = ahi[2]; a[7] = ahi[3];
                #pragma unroll
                for (int dt = 0; dt < 4; ++dt) {
                    s8 bv = *(const s8*)&Vb[dt * 16 + l16][ks * 32 + quad * 8];
                    os_[dt] = MFMA16(a, bv, os_[dt]);
                }
            }
        }
        __syncthreads();
        if (pf) {
            #pragma unroll
            for (int tl = 0; tl < 4; ++tl) {
                int g = tid + tl * 512, row = g >> 5, grp = g & 31;
                *(s8*)&Kc[row][grp * 8] = kcp[tl];
            }
            int row = tid >> 3, grp = tid & 7;
            *(s8*)&Ksf[row][grp * 8] = ksp;
            *(s8*)&Vb[row][grp * 8] = vp;
        }
        __syncthreads();
    }

    #pragma unroll
    for (int reg = 0; reg < 4; ++reg) {
        float l1 = lc[reg], l2 = ls_[reg];
        l1 += __shfl_xor(l1, 1); l1 += __shfl_xor(l1, 2);
        l1 += __shfl_xor(l1, 4); l1 += __shfl_xor(l1, 8);
        l2 += __shfl_xor(l2, 1); l2 += __shfl_xor(l2, 2);
        l2 += __shfl_xor(l2, 4); l2 += __shfl_xor(l2, 8);
        const float i1 = 1.f / l1, i2 = 1.f / l2;
        const int t = rb + quad * 4 + reg;
        #pragma unroll
        for (int dt = 0; dt < 4; ++dt) {
            size_t idx = (size_t)(b * T_ + t) * C_ + h * HD_ + dt * 16 + l16;
            float cv = ocv[dt][reg] + oc[dt][reg] * i1 + x[idx];
            cval_bf[idx] = __float2bfloat16(cv);
            float sv = os_[dt][reg] * i2;
            sval_bf[idx] = __float2bfloat16(sv);
        }
    }
}

// ---------------- fused dual gate GEMM + sigmoid + combine -> gated bf16 ----------------
__global__ __launch_bounds__(256) void gatefuse_kernel(
    const bf16* __restrict__ svalb, const bf16* __restrict__ cvalb,
    const bf16* __restrict__ WTgs, const bf16* __restrict__ WTgc,
    const float* __restrict__ bgs, const float* __restrict__ bgc,
    bf16* __restrict__ gated)
{
    __shared__ short Sb[128 * 64], Cb[128 * 64], W1b[64 * 64], W2b[64 * 64];
    const int tid = threadIdx.x;
    const int wave = tid >> 6, lane = tid & 63;
    const int quad = lane >> 4, l16 = lane & 15;
    const int sx = l16 & 7;
    const int lrow = lane >> 3;
    const int lcol = ((lane & 7) ^ lrow) * 8;
    const int n0 = blockIdx.y * 64, m0 = blockIdx.x * 128;
    f4 aS[2][4], aC[2][4];
    #pragma unroll
    for (int mt = 0; mt < 2; ++mt)
        #pragma unroll
        for (int nt = 0; nt < 4; ++nt) { aS[mt][nt] = (f4)0.f; aC[mt][nt] = (f4)0.f; }

    for (int k0 = 0; k0 < C_; k0 += 64) {
        #pragma unroll
        for (int i = 0; i < 4; ++i) {
            int c = wave * 4 + i;
            const size_t rowoff = (size_t)(m0 + c * 8 + lrow) * C_ + k0 + lcol;
            gl16(&svalb[rowoff], &Sb[c * 512]);
            gl16(&cvalb[rowoff], &Cb[c * 512]);
        }
        #pragma unroll
        for (int i = 0; i < 2; ++i) {
            int c = wave * 2 + i;
            const size_t rowoff = (size_t)(n0 + c * 8 + lrow) * C_ + k0 + lcol;
            gl16(&WTgs[rowoff], &W1b[c * 512]);
            gl16(&WTgc[rowoff], &W2b[c * 512]);
        }
        __syncthreads();
        #pragma unroll
        for (int ks = 0; ks < 2; ++ks) {
            const int g8 = ((ks * 4 + quad) ^ sx) * 8;
            s8 s0f = *(const s8*)&Sb[(wave * 32 + l16) * 64 + g8];
            s8 s1f = *(const s8*)&Sb[(wave * 32 + 16 + l16) * 64 + g8];
            s8 c0f = *(const s8*)&Cb[(wave * 32 + l16) * 64 + g8];
            s8 c1f = *(const s8*)&Cb[(wave * 32 + 16 + l16) * 64 + g8];
            #pragma unroll
            for (int nt = 0; nt < 4; ++nt) {
                s8 w1 = *(const s8*)&W1b[(nt * 16 + l16) * 64 + g8];
                s8 w2 = *(const s8*)&W2b[(nt * 16 + l16) * 64 + g8];
                aS[0][nt] = MFMA16(s0f, w1, aS[0][nt]);
                aS[1][nt] = MFMA16(s1f, w1, aS[1][nt]);
                aC[0][nt] = MFMA16(c0f, w2, aC[0][nt]);
                aC[1][nt] = MFMA16(c1f, w2, aC[1][nt]);
            }
        }
        __syncthreads();
    }
    #pragma unroll
    for (int mt = 0; mt < 2; ++mt)
        #pragma unroll
        for (int nt = 0; nt < 4; ++nt) {
            int col = n0 + nt * 16 + l16;
            float b1 = bgs[col], b2 = bgc[col];
            #pragma unroll
            for (int reg = 0; reg < 4; ++reg) {
                int row = m0 + wave * 32 + mt * 16 + quad * 4 + reg;
                size_t idx = (size_t)row * C_ + col;
                float gs = 1.f / (1.f + __expf(-(aS[mt][nt][reg] + b1)));
                float gc = 1.f / (1.f + __expf(-(aC[mt][nt][reg] + b2)));
                float cvv = __bfloat162float(cvalb[idx]);
                float svv = __bfloat162float(svalb[idx]);
                gated[idx] = __float2bfloat16(gs * cvv + gc * svv);
            }
        }
}

extern "C" void kernel_launch(void* const* d_in, const int* in_sizes, int n_in,
                              void* d_out, int out_size, void* d_ws, size_t ws_size,
                              hipStream_t stream)
{
    const float* x      = (const float*)d_in[0];
    const float* y      = (const float*)d_in[1];
    // d_in[2]: attn_x_mask — structurally causal tril, computed inline
    const float* Wqkv_x = (const float*)d_in[3];
    const float* bqkv_x = (const float*)d_in[4];
    const float* Wqkv_y = (const float*)d_in[5];
    const float* bqkv_y = (const float*)d_in[6];
    const float* w4x    = (const float*)d_in[7];
    const float* w4y    = (const float*)d_in[8];
    const float* w4xy   = (const float*)d_in[9];
    const float* Wgs    = (const float*)d_in[10];
    const float* bgs    = (const float*)d_in[11];
    const float* Wgc    = (const float*)d_in[12];
    const float* bgc    = (const float*)d_in[13];
    const float* Wp     = (const float*)d_in[14];
    const float* bp     = (const float*)d_in[15];

    // Workspace (f-word offsets; proven layout)
    float* ws = (float*)d_ws;
    bf16*  qkv_x_bf = (bf16*)(ws + 0);           // 6,291,456 bf16
    bf16*  qkv_y_bf = (bf16*)(ws + 3145728);     // 1,572,864 bf16
    bf16*  gated_bf = (bf16*)(ws + 3932160);
    bf16*  cval_bf  = (bf16*)(ws + 5242880);
    bf16*  x2y_bf   = (bf16*)(ws + 12320768);    // 8,388,608 bf16 (written by catt3rv)
    bf16*  x_bf     = x2y_bf;                    //   pre-QKV reuse
    bf16*  y_bf     = (bf16*)(ws + 13369344);    //   pre-QKV reuse
    bf16*  vTx_bf   = (bf16*)(ws + 20709376);    // 2,097,152 bf16
    bf16*  vTy_bf   = (bf16*)(ws + 21757952);    // 524,288 bf16
    float* psum_    = ws + 22020096;             // 131,072 f
    bf16*  qw_bf    = (bf16*)(ws + 26214400);    // (dead slot; reused as sval)
    bf16*  sval_bf  = qw_bf;
    bf16*  WT_x     = (bf16*)(ws + 27262976);    // 786,432 bf16
    bf16*  WT_y     = (bf16*)(ws + 27656192);
    bf16*  WT_gs    = (bf16*)(ws + 28049408);    // 262,144 bf16
    bf16*  WT_gc    = (bf16*)(ws + 28180480);
    bf16*  WT_p    = (bf16*)(ws + 28311552);
    float* rowsum_  = ws + 28491776;             // 32,768 f

    // 0: one prep dispatch
    prep_kernel<<<1856, 256, 0, stream>>>(
        Wqkv_x, Wqkv_y, Wgs, Wgc, Wp, x, y,
        WT_x, WT_y, WT_gs, WT_gc, WT_p, x_bf, y_bf);

    // 1: QKV projections (x + y merged, 128x128 tiles, XCD-swizzled)
    qkv_gemm_kernel<<<480, 256, 0, stream>>>(
        x_bf, y_bf, WT_x, WT_y, bqkv_x, bqkv_y, qkv_x_bf, qkv_y_bf);

    // 2: catt1/catt2 inline + logits + row softmax + V transposes (merged)
    catt3rv_kernel<<<1152, 256, 0, stream>>>(
        qkv_x_bf, qkv_y_bf, w4x, w4y, w4xy, x2y_bf, rowsum_, psum_, vTx_bf, vTy_bf);

    // 3: flash (colfin folded in)
    flash15_kernel<<<dim3(32, 8), 512, 0, stream>>>(
        x2y_bf, rowsum_, psum_, vTx_bf, vTy_bf, qkv_x_bf, x, cval_bf, sval_bf);

    // 4: fused gates (global_load_lds staging)
    gatefuse_kernel<<<dim3(32, 8), 256, 0, stream>>>(
        sval_bf, cval_bf, WT_gs, WT_gc, bgs, bgc, gated_bf);

    // 5: out = gated @ Wp + bp
    gemm_staged_kernel<float><<<dim3(32, 8), 256, 0, stream>>>(
        gated_bf, WT_p, bp, (float*)d_out, C_, C_);
}

// Round 15
// 201.092 us; speedup vs baseline: 1.0198x; 1.0198x over previous
//
#include <hip/hip_runtime.h>
#include <hip/hip_bf16.h>

typedef __hip_bfloat16 bf16;
using f4 = __attribute__((ext_vector_type(4))) float;
using s8 = __attribute__((ext_vector_type(8))) short;
using s4 = __attribute__((ext_vector_type(4))) short;

__device__ __forceinline__ void storeOut(float* p, float v) { *p = v; }
__device__ __forceinline__ void storeOut(bf16* p, float v) { *p = __float2bfloat16(v); }
__device__ __forceinline__ short bfs(float x) { return __builtin_bit_cast(short, __float2bfloat16(x)); }

// async 16-byte global->LDS DMA; lds base must be wave-uniform (HW scatters lane*16)
__device__ __forceinline__ void gl16(const void* g, void* l) {
    __builtin_amdgcn_global_load_lds(
        (const __attribute__((address_space(1))) unsigned int*)g,
        (__attribute__((address_space(3))) unsigned int*)l, 16, 0, 0);
}

constexpr int B_ = 4, T_ = 1024, M_ = 256, C_ = 512, H_ = 8, HD_ = 64, C3_ = 1536;

#define MFMA16(a, b, c) __builtin_amdgcn_mfma_f32_16x16x32_bf16((a), (b), (c), 0, 0, 0)

// ---------------- prep: 5 weight transposes (fp32 KxN -> bf16 NxK) + 2 converts ----------------
__global__ __launch_bounds__(256) void prep_kernel(
    const float* __restrict__ Wqkv_x, const float* __restrict__ Wqkv_y,
    const float* __restrict__ Wgs, const float* __restrict__ Wgc, const float* __restrict__ Wp,
    const float* __restrict__ x, const float* __restrict__ y,
    bf16* __restrict__ WT_x, bf16* __restrict__ WT_y, bf16* __restrict__ WT_gs,
    bf16* __restrict__ WT_gc, bf16* __restrict__ WT_p,
    bf16* __restrict__ x_bf, bf16* __restrict__ y_bf)
{
    __shared__ float Ls[64][65];
    const int tid = threadIdx.x;
    const int bid = blockIdx.x;
    if (bid < 576) {
        const float* W; bf16* WT; int N, t;
        if (bid < 192)      { W = Wqkv_x; WT = WT_x;  N = C3_; t = bid; }
        else if (bid < 384) { W = Wqkv_y; WT = WT_y;  N = C3_; t = bid - 192; }
        else if (bid < 448) { W = Wgs;    WT = WT_gs; N = C_;  t = bid - 384; }
        else if (bid < 512) { W = Wgc;    WT = WT_gc; N = C_;  t = bid - 448; }
        else                { W = Wp;     WT = WT_p;  N = C_;  t = bid - 512; }
        const int K = C_;
        const int tw = N >> 6;
        const int n0 = (t % tw) * 64, k0 = (t / tw) * 64;
        for (int i = tid; i < 1024; i += 256) {
            int kr = i >> 4, ng = i & 15;
            float4 v = *(const float4*)&W[(size_t)(k0 + kr) * N + n0 + ng * 4];
            Ls[ng * 4 + 0][kr] = v.x; Ls[ng * 4 + 1][kr] = v.y;
            Ls[ng * 4 + 2][kr] = v.z; Ls[ng * 4 + 3][kr] = v.w;
        }
        __syncthreads();
        for (int i = tid; i < 512; i += 256) {
            int n = i >> 3, kg = i & 7;
            s8 r;
            #pragma unroll
            for (int j = 0; j < 8; ++j) r[j] = bfs(Ls[n][kg * 8 + j]);
            *(s8*)&WT[(size_t)(n0 + n) * K + k0 + kg * 8] = r;
        }
    } else if (bid < 1600) {
        int i = (bid - 576) * 2048 + tid * 8;
        s8 r;
        #pragma unroll
        for (int j = 0; j < 8; ++j) r[j] = bfs(x[i + j]);
        *(s8*)&x_bf[i] = r;
    } else {
        int i = (bid - 1600) * 2048 + tid * 8;
        s8 r;
        #pragma unroll
        for (int j = 0; j < 8; ++j) r[j] = bfs(y[i + j]);
        *(s8*)&y_bf[i] = r;
    }
}

// ---------------- shared GEMM body (128x64 tile) — global_load_lds(16B) staging into
// LINEAR LDS with XOR-swizzle: slot (row, g) holds global colgrp g^(row&7). ----------------
template <typename OT>
__device__ __forceinline__ void gemm_body(
    short* __restrict__ Asb, short* __restrict__ Bsb,
    const bf16* __restrict__ A, const bf16* __restrict__ WT, const float* __restrict__ bias,
    OT* __restrict__ Cmat, int N, int K, int m0, int n0)
{
    const int tid = threadIdx.x;
    const int wave = tid >> 6, lane = tid & 63;
    const int quad = lane >> 4, l16 = lane & 15;
    const int sx = l16 & 7;
    const int lrow = lane >> 3;                    // 0..7 within chunk
    const int lcol = ((lane & 7) ^ lrow) * 8;      // swizzled-source col (shorts)
    f4 acc[2][4];
    #pragma unroll
    for (int mt = 0; mt < 2; ++mt)
        #pragma unroll
        for (int nt = 0; nt < 4; ++nt) acc[mt][nt] = (f4)0.f;

    for (int k0 = 0; k0 < K; k0 += 64) {
        #pragma unroll
        for (int i = 0; i < 4; ++i) {
            int c = wave * 4 + i;
            gl16(&A[(size_t)(m0 + c * 8 + lrow) * K + k0 + lcol], &Asb[c * 512]);
        }
        #pragma unroll
        for (int i = 0; i < 2; ++i) {
            int c = wave * 2 + i;
            gl16(&WT[(size_t)(n0 + c * 8 + lrow) * K + k0 + lcol], &Bsb[c * 512]);
        }
        __syncthreads();
        #pragma unroll
        for (int ks = 0; ks < 2; ++ks) {
            const int g8 = ((ks * 4 + quad) ^ sx) * 8;
            s8 a0 = *(const s8*)&Asb[(wave * 32 + l16) * 64 + g8];
            s8 a1 = *(const s8*)&Asb[(wave * 32 + 16 + l16) * 64 + g8];
            #pragma unroll
            for (int nt = 0; nt < 4; ++nt) {
                s8 bv = *(const s8*)&Bsb[(nt * 16 + l16) * 64 + g8];
                acc[0][nt] = MFMA16(a0, bv, acc[0][nt]);
                acc[1][nt] = MFMA16(a1, bv, acc[1][nt]);
            }
        }
        __syncthreads();
    }
    #pragma unroll
    for (int mt = 0; mt < 2; ++mt)
        #pragma unroll
        for (int nt = 0; nt < 4; ++nt) {
            int col = n0 + nt * 16 + l16;
            float bb = bias[col];
            #pragma unroll
            for (int reg = 0; reg < 4; ++reg) {
                int row = m0 + wave * 32 + mt * 16 + quad * 4 + reg;
                storeOut(&Cmat[(size_t)row * N + col], acc[mt][nt][reg] + bb);
            }
        }
}

template <typename OT>
__global__ __launch_bounds__(256) void gemm_staged_kernel(
    const bf16* __restrict__ A, const bf16* __restrict__ WT, const float* __restrict__ bias,
    OT* __restrict__ Cmat, int N, int K)
{
    __shared__ short Asb[128 * 64];
    __shared__ short Bsb[64 * 64];
    gemm_body<OT>(Asb, Bsb, A, WT, bias, Cmat, N, K, blockIdx.x * 128, blockIdx.y * 64);
}

// ---------------- merged QKV x + y projection (one dispatch, 960 blocks)
// + XCD-aware bijective block swizzle (960 % 8 == 0) for L2 panel locality ----------------
__global__ __launch_bounds__(256) void qkv_gemm_kernel(
    const bf16* __restrict__ x_bf, const bf16* __restrict__ y_bf,
    const bf16* __restrict__ WTx, const bf16* __restrict__ WTy,
    const float* __restrict__ bqx, const float* __restrict__ bqy,
    bf16* __restrict__ qkv_x, bf16* __restrict__ qkv_y)
{
    __shared__ short Asb[128 * 64];
    __shared__ short Bsb[64 * 64];
    const int t = (blockIdx.x & 7) * 120 + (blockIdx.x >> 3);   // XCD swizzle (bijective)
    if (t < 768) {
        gemm_body<bf16>(Asb, Bsb, x_bf, WTx, bqx, qkv_x, C3_, C_, (t & 31) * 128, (t >> 5) * 64);
    } else {
        const int u = t - 768;
        gemm_body<bf16>(Asb, Bsb, y_bf, WTy, bqy, qkv_y, C3_, C_, (u & 7) * 128, (u >> 3) * 64);
    }
}

// ---------------- catt3rv: inline catt1/catt2 + logits + row softmax + V transposes ----------------
__global__ __launch_bounds__(256) void catt3rv_kernel(
    const bf16* __restrict__ qkv_x, const bf16* __restrict__ qkv_y,
    const float* __restrict__ w4x, const float* __restrict__ w4y,
    const float* __restrict__ w4xy,
    bf16* __restrict__ x2y, float* __restrict__ rowsum_, float* __restrict__ psum,
    bf16* __restrict__ vTx, bf16* __restrict__ vTy)
{
    __shared__ float redc[4][256];
    __shared__ float c1s[64];
    __shared__ float c2s[256];
    __shared__ short Ls[64][68];
    const int tid = threadIdx.x;
    int bid = blockIdx.x;

    if (bid >= 512) {
        int vb = bid - 512;
        const bf16* qkv; bf16* vT; int Nrows, bh, t0;
        if (vb < 512) { qkv = qkv_x; vT = vTx; Nrows = T_; bh = vb >> 4; t0 = (vb & 15) * 64; }
        else { vb -= 512; qkv = qkv_y; vT = vTy; Nrows = M_; bh = vb >> 2; t0 = (vb & 3) * 64; }
        const int b = bh >> 3, h = bh & 7;
        for (int i = tid; i < 4096; i += 256) {
            int tl = i >> 6, d = i & 63;
            Ls[d][tl] = __builtin_bit_cast(short,
                qkv[(size_t)(b * Nrows + t0 + tl) * C3_ + 2 * C_ + h * HD_ + d]);
        }
        __syncthreads();
        for (int i = tid; i < 4096; i += 256) {
            int d = i >> 6, tl = i & 63;
            vT[((size_t)bh * 64 + d) * Nrows + t0 + tl] = __builtin_bit_cast(bf16, Ls[d][tl]);
        }
        return;
    }

    const int wave = tid >> 6, lane = tid & 63;
    const int quad = lane >> 4, l16 = lane & 15;
    const int bh = bid >> 4, b = bh >> 3, h = bh & 7;
    const int t0 = (bid & 15) * 64;

    {
        const bf16* row = qkv_y + (size_t)(b * M_ + tid) * C3_ + h * HD_;
        const float* w = w4y + h * HD_;
        float s = 0.f;
        #pragma unroll
        for (int d = 0; d < HD_; ++d) s = fmaf(__bfloat162float(row[d]), w[d], s);
        c2s[tid] = s;
    }
    if (tid < 64) {
        const bf16* row = qkv_x + (size_t)(b * T_ + t0 + tid) * C3_ + h * HD_;
        const float* w = w4x + h * HD_;
        float s = 0.f;
        #pragma unroll
        for (int d = 0; d < HD_; ++d) s = fmaf(__bfloat162float(row[d]), w[d], s);
        c1s[tid] = s;
    }

    f4 sc[4][4];
    #pragma unroll
    for (int mt = 0; mt < 4; ++mt)
        #pragma unroll
        for (int nt = 0; nt < 4; ++nt) sc[mt][nt] = (f4)0.f;

    const bf16* ap = qkv_x + (size_t)(b * T_ + t0 + wave * 16 + l16) * C3_ + h * HD_ + quad * 8;
    s8 a0r = *(const s8*)ap;
    s8 a1r = *(const s8*)(ap + 32);
    const float* wx = w4xy + h * HD_ + quad * 8;
    s8 a0, a1;
    #pragma unroll
    for (int j = 0; j < 8; ++j) {
        a0[j] = bfs(__bfloat162float(__builtin_bit_cast(bf16, a0r[j])) * wx[j]);
        a1[j] = bfs(__bfloat162float(__builtin_bit_cast(bf16, a1r[j])) * wx[j + 32]);
    }
    const bf16* bp = qkv_y + (size_t)(b * M_ + l16) * C3_ + C_ + h * HD_ + quad * 8;
    #pragma unroll
    for (int mt = 0; mt < 4; ++mt)
        #pragma unroll
        for (int nt = 0; nt < 4; ++nt) {
            const bf16* bq = bp + (size_t)(mt * 64 + nt * 16) * C3_;
            sc[mt][nt] = MFMA16(a0, *(const s8*)bq, sc[mt][nt]);
            sc[mt][nt] = MFMA16(a1, *(const s8*)(bq + 32), sc[mt][nt]);
        }
    __syncthreads();   // c1s/c2s ready

    float c1[4];
    #pragma unroll
    for (int reg = 0; reg < 4; ++reg)
        c1[reg] = c1s[wave * 16 + quad * 4 + reg];
    #pragma unroll
    for (int mt = 0; mt < 4; ++mt)
        #pragma unroll
        for (int nt = 0; nt < 4; ++nt) {
            float c2 = c2s[mt * 64 + nt * 16 + l16];
            #pragma unroll
            for (int reg = 0; reg < 4; ++reg)
                sc[mt][nt][reg] = __expf(sc[mt][nt][reg] * 0.125f + c1[reg] + c2);
        }

    #pragma unroll
    for (int reg = 0; reg < 4; ++reg) {
        float rs = 0.f;
        #pragma unroll
        for (int mt = 0; mt < 4; ++mt)
            #pragma unroll
            for (int nt = 0; nt < 4; ++nt) rs += sc[mt][nt][reg];
        rs += __shfl_xor(rs, 1); rs += __shfl_xor(rs, 2);
        rs += __shfl_xor(rs, 4); rs += __shfl_xor(rs, 8);
        const int t = t0 + wave * 16 + quad * 4 + reg;
        if (l16 == 0) rowsum_[bh * T_ + t] = rs;
        const float ri = 1.f / rs;
        #pragma unroll
        for (int mt = 0; mt < 4; ++mt)
            #pragma unroll
            for (int nt = 0; nt < 4; ++nt)
                x2y[((size_t)bh * T_ + t) * M_ + mt * 64 + nt * 16 + l16] =
                    __float2bfloat16(sc[mt][nt][reg] * ri);
    }

    #pragma unroll
    for (int mt = 0; mt < 4; ++mt)
        #pragma unroll
        for (int nt = 0; nt < 4; ++nt) {
            float es = sc[mt][nt][0] + sc[mt][nt][1] + sc[mt][nt][2] + sc[mt][nt][3];
            es += __shfl_xor(es, 16);
            es += __shfl_xor(es, 32);
            if (quad == 0) redc[wave][mt * 64 + nt * 16 + l16] = es;
        }
    __syncthreads();
    psum[((size_t)bh * 16 + (bid & 15)) * M_ + tid] =
        redc[0][tid] + redc[1][tid] + redc[2][tid] + redc[3][tid];
}

// ---------------- flash15: proven (unchanged) ----------------
__global__ __launch_bounds__(512) void flash15_kernel(
    const bf16* __restrict__ x2y, const float* __restrict__ rowsum_,
    const float* __restrict__ psum_,
    const bf16* __restrict__ vTx, const bf16* __restrict__ vTy,
    const bf16* __restrict__ qkv_x, const float* __restrict__ x,
    bf16* __restrict__ cval_bf, bf16* __restrict__ sval_bf)
{
    __shared__ short Kc[64][264];
    __shared__ short Ksf[64][72];
    __shared__ short Vb[64][72];
    __shared__ short Ps[8][16][68];
    __shared__ float cinv[256];
    const int tid = threadIdx.x;
    const int wave = tid >> 6, lane = tid & 63;
    const int quad = lane >> 4, l16 = lane & 15;
    const int bh = blockIdx.x, b = bh >> 3, h = bh & 7;
    const int p = blockIdx.y;
    const int jt = (wave < 4) ? p : (15 - p);
    const int rb = jt * 64 + (wave & 3) * 16;
    const int nst = 16 - p;

    if (tid < 256) {
        float s = 0.f;
        #pragma unroll
        for (int ch = 0; ch < 16; ++ch) s += psum_[(size_t)(bh * 16 + ch) * M_ + tid];
        cinv[tid] = 1.f / s;
    }

    s8 qc[8], qs[2];
    {
        const bf16* qp = x2y + (size_t)(bh * T_ + rb + l16) * M_ + quad * 8;
        #pragma unroll
        for (int f = 0; f < 8; ++f) qc[f] = *(const s8*)(qp + f * 32);
        const bf16* qsp = qkv_x + (size_t)(b * T_ + rb + l16) * C3_ + h * HD_ + quad * 8;
        qs[0] = *(const s8*)qsp;
        qs[1] = *(const s8*)(qsp + 32);
    }

    #pragma unroll
    for (int tl = 0; tl < 4; ++tl) {
        int g = tid + tl * 512, row = g >> 5, grp = g & 31;
        *(s8*)&Kc[row][grp * 8] = *(const s8*)&x2y[(size_t)(bh * T_ + row) * M_ + grp * 8];
    }
    {
        int row = tid >> 3, grp = tid & 7;
        *(s8*)&Ksf[row][grp * 8] =
            *(const s8*)&qkv_x[(size_t)(b * T_ + row) * C3_ + C_ + h * HD_ + grp * 8];
        *(s8*)&Vb[row][grp * 8] = *(const s8*)&vTx[(size_t)(bh * 64 + row) * T_ + grp * 8];
    }
    __syncthreads();

    f4 ocv[4];
    #pragma unroll
    for (int dt = 0; dt < 4; ++dt) ocv[dt] = (f4)0.f;
    {
        const bf16* vb = vTy + (size_t)(bh * 64 + l16) * M_ + quad * 8;
        #pragma unroll
        for (int f = 0; f < 8; ++f)
            #pragma unroll
            for (int dt = 0; dt < 4; ++dt) {
                s8 bv = *(const s8*)(vb + (size_t)dt * 16 * M_ + f * 32);
                ocv[dt] = MFMA16(qc[f], bv, ocv[dt]);
            }
    }

    #pragma unroll
    for (int f = 0; f < 8; ++f) {
        const float* cp = &cinv[f * 32 + quad * 8];
        s8 q = qc[f], r;
        #pragma unroll
        for (int j = 0; j < 8; ++j)
            r[j] = bfs(__bfloat162float(__builtin_bit_cast(bf16, q[j])) * cp[j]);
        qc[f] = r;
    }

    f4 oc[4], os_[4];
    float lc[4] = {0.f, 0.f, 0.f, 0.f}, ls_[4] = {0.f, 0.f, 0.f, 0.f};
    #pragma unroll
    for (int dt = 0; dt < 4; ++dt) { oc[dt] = (f4)0.f; os_[dt] = (f4)0.f; }

    for (int st = 0; st < nst; ++st) {
        const int s0 = st * 64;
        const bool pf = (st + 1) < nst;
        s8 kcp[4], ksp, vp;
        if (pf) {
            const int sn = s0 + 64;
            #pragma unroll
            for (int tl = 0; tl < 4; ++tl) {
                int g = tid + tl * 512, row = g >> 5, grp = g & 31;
                kcp[tl] = *(const s8*)&x2y[(size_t)(bh * T_ + sn + row) * M_ + grp * 8];
            }
            int row = tid >> 3, grp = tid & 7;
            ksp = *(const s8*)&qkv_x[(size_t)(b * T_ + sn + row) * C3_ + C_ + h * HD_ + grp * 8];
            vp = *(const s8*)&vTx[(size_t)(bh * 64 + row) * T_ + sn + grp * 8];
        }
        if (st <= jt) {
            float rsS[4];
            #pragma unroll
            for (int nt = 0; nt < 4; ++nt)
                rsS[nt] = rowsum_[bh * T_ + s0 + nt * 16 + l16] * 0.0625f;
            f4 sc[4];
            #pragma unroll
            for (int nt = 0; nt < 4; ++nt) sc[nt] = (f4)0.f;
            #pragma unroll
            for (int f = 0; f < 8; ++f)
                #pragma unroll
                for (int nt = 0; nt < 4; ++nt) {
                    s8 bv = *(const s8*)&Kc[nt * 16 + l16][f * 32 + quad * 8];
                    sc[nt] = MFMA16(qc[f], bv, sc[nt]);
                }
            f4 ss[4];
            #pragma unroll
            for (int nt = 0; nt < 4; ++nt) ss[nt] = (f4)0.f;
            #pragma unroll
            for (int f = 0; f < 2; ++f)
                #pragma unroll
                for (int nt = 0; nt < 4; ++nt) {
                    s8 bv = *(const s8*)&Ksf[nt * 16 + l16][f * 32 + quad * 8];
                    ss[nt] = MFMA16(qs[f], bv, ss[nt]);
                }
            #pragma unroll
            for (int reg = 0; reg < 4; ++reg) {
                const int t_g = rb + quad * 4 + reg;
                #pragma unroll
                for (int nt = 0; nt < 4; ++nt) {
                    float pv = (s0 + nt * 16 + l16 <= t_g) ? __expf(sc[nt][reg] * rsS[nt]) : 0.f;
                    lc[reg] += pv;
                    Ps[wave][quad * 4 + reg][nt * 16 + l16] = bfs(pv);
                }
            }
            #pragma unroll
            for (int ks = 0; ks < 2; ++ks) {
                const short* pp = &Ps[wave][l16][ks * 32 + quad * 8];
                s4 alo = *(const s4*)pp;
                s4 ahi = *(const s4*)(pp + 4);
                s8 a;
                a[0] = alo[0]; a[1] = alo[1]; a[2] = alo[2]; a[3] = alo[3];
                a[4] = ahi[0]; a[5] = ahi[1]; a[6] = ahi[2]; a[7] = ahi[3];
                #pragma unroll
                for (int dt = 0; dt < 4; ++dt) {
                    s8 bv = *(const s8*)&Vb[dt * 16 + l16][ks * 32 + quad * 8];
                    oc[dt] = MFMA16(a, bv, oc[dt]);
                }
            }
            #pragma unroll
            for (int reg = 0; reg < 4; ++reg) {
                const int t_g = rb + quad * 4 + reg;
                #pragma unroll
                for (int nt = 0; nt < 4; ++nt) {
                    float pv = (s0 + nt * 16 + l16 <= t_g) ? __expf(ss[nt][reg] * 0.125f) : 0.f;
                    ls_[reg] += pv;
                    Ps[wave][quad * 4 + reg][nt * 16 + l16] = bfs(pv);
                }
            }
            #pragma unroll
            for (int ks = 0; ks < 2; ++ks) {
                const short* pp = &Ps[wave][l16][ks * 32 + quad * 8];
                s4 alo = *(const s4*)pp;
                s4 ahi = *(const s4*)(pp + 4);
                s8 a;
                a[0] = alo[0]; a[1] = alo[1]; a[2] = alo[2]; a[3] = alo[3];
                a[4] = ahi[0]; a[5] = ahi[1]; a[6] = ahi[2]; a[7] = ahi[3];
                #pragma unroll
                for (int dt = 0; dt < 4; ++dt) {
                    s8 bv = *(const s8*)&Vb[dt * 16 + l16][ks * 32 + quad * 8];
                    os_[dt] = MFMA16(a, bv, os_[dt]);
                }
            }
        }
        __syncthreads();
        if (pf) {
            #pragma unroll
            for (int tl = 0; tl < 4; ++tl) {
                int g = tid + tl * 512, row = g >> 5, grp = g & 31;
                *(s8*)&Kc[row][grp * 8] = kcp[tl];
            }
            int row = tid >> 3, grp = tid & 7;
            *(s8*)&Ksf[row][grp * 8] = ksp;
            *(s8*)&Vb[row][grp * 8] = vp;
        }
        __syncthreads();
    }

    #pragma unroll
    for (int reg = 0; reg < 4; ++reg) {
        float l1 = lc[reg], l2 = ls_[reg];
        l1 += __shfl_xor(l1, 1); l1 += __shfl_xor(l1, 2);
        l1 += __shfl_xor(l1, 4); l1 += __shfl_xor(l1, 8);
        l2 += __shfl_xor(l2, 1); l2 += __shfl_xor(l2, 2);
        l2 += __shfl_xor(l2, 4); l2 += __shfl_xor(l2, 8);
        const float i1 = 1.f / l1, i2 = 1.f / l2;
        const int t = rb + quad * 4 + reg;
        #pragma unroll
        for (int dt = 0; dt < 4; ++dt) {
            size_t idx = (size_t)(b * T_ + t) * C_ + h * HD_ + dt * 16 + l16;
            float cv = ocv[dt][reg] + oc[dt][reg] * i1 + x[idx];
            cval_bf[idx] = __float2bfloat16(cv);
            float sv = os_[dt][reg] * i2;
            sval_bf[idx] = __float2bfloat16(sv);
        }
    }
}

// ---------------- fused dual gate GEMM + sigmoid + combine -> gated bf16 ----------------
__global__ __launch_bounds__(256) void gatefuse_kernel(
    const bf16* __restrict__ svalb, const bf16* __restrict__ cvalb,
    const bf16* __restrict__ WTgs, const bf16* __restrict__ WTgc,
    const float* __restrict__ bgs, const float* __restrict__ bgc,
    bf16* __restrict__ gated)
{
    __shared__ short Sb[128 * 64], Cb[128 * 64], W1b[64 * 64], W2b[64 * 64];
    const int tid = threadIdx.x;
    const int wave = tid >> 6, lane = tid & 63;
    const int quad = lane >> 4, l16 = lane & 15;
    const int sx = l16 & 7;
    const int lrow = lane >> 3;
    const int lcol = ((lane & 7) ^ lrow) * 8;
    const int n0 = blockIdx.y * 64, m0 = blockIdx.x * 128;
    f4 aS[2][4], aC[2][4];
    #pragma unroll
    for (int mt = 0; mt < 2; ++mt)
        #pragma unroll
        for (int nt = 0; nt < 4; ++nt) { aS[mt][nt] = (f4)0.f; aC[mt][nt] = (f4)0.f; }

    for (int k0 = 0; k0 < C_; k0 += 64) {
        #pragma unroll
        for (int i = 0; i < 4; ++i) {
            int c = wave * 4 + i;
            const size_t rowoff = (size_t)(m0 + c * 8 + lrow) * C_ + k0 + lcol;
            gl16(&svalb[rowoff], &Sb[c * 512]);
            gl16(&cvalb[rowoff], &Cb[c * 512]);
        }
        #pragma unroll
        for (int i = 0; i < 2; ++i) {
            int c = wave * 2 + i;
            const size_t rowoff = (size_t)(n0 + c * 8 + lrow) * C_ + k0 + lcol;
            gl16(&WTgs[rowoff], &W1b[c * 512]);
            gl16(&WTgc[rowoff], &W2b[c * 512]);
        }
        __syncthreads();
        #pragma unroll
        for (int ks = 0; ks < 2; ++ks) {
            const int g8 = ((ks * 4 + quad) ^ sx) * 8;
            s8 s0f = *(const s8*)&Sb[(wave * 32 + l16) * 64 + g8];
            s8 s1f = *(const s8*)&Sb[(wave * 32 + 16 + l16) * 64 + g8];
            s8 c0f = *(const s8*)&Cb[(wave * 32 + l16) * 64 + g8];
            s8 c1f = *(const s8*)&Cb[(wave * 32 + 16 + l16) * 64 + g8];
            #pragma unroll
            for (int nt = 0; nt < 4; ++nt) {
                s8 w1 = *(const s8*)&W1b[(nt * 16 + l16) * 64 + g8];
                s8 w2 = *(const s8*)&W2b[(nt * 16 + l16) * 64 + g8];
                aS[0][nt] = MFMA16(s0f, w1, aS[0][nt]);
                aS[1][nt] = MFMA16(s1f, w1, aS[1][nt]);
                aC[0][nt] = MFMA16(c0f, w2, aC[0][nt]);
                aC[1][nt] = MFMA16(c1f, w2, aC[1][nt]);
            }
        }
        __syncthreads();
    }
    #pragma unroll
    for (int mt = 0; mt < 2; ++mt)
        #pragma unroll
        for (int nt = 0; nt < 4; ++nt) {
            int col = n0 + nt * 16 + l16;
            float b1 = bgs[col], b2 = bgc[col];
            #pragma unroll
            for (int reg = 0; reg < 4; ++reg) {
                int row = m0 + wave * 32 + mt * 16 + quad * 4 + reg;
                size_t idx = (size_t)row * C_ + col;
                float gs = 1.f / (1.f + __expf(-(aS[mt][nt][reg] + b1)));
                float gc = 1.f / (1.f + __expf(-(aC[mt][nt][reg] + b2)));
                float cvv = __bfloat162float(cvalb[idx]);
                float svv = __bfloat162float(svalb[idx]);
                gated[idx] = __float2bfloat16(gs * cvv + gc * svv);
            }
        }
}

extern "C" void kernel_launch(void* const* d_in, const int* in_sizes, int n_in,
                              void* d_out, int out_size, void* d_ws, size_t ws_size,
                              hipStream_t stream)
{
    const float* x      = (const float*)d_in[0];
    const float* y      = (const float*)d_in[1];
    // d_in[2]: attn_x_mask — structurally causal tril, computed inline
    const float* Wqkv_x = (const float*)d_in[3];
    const float* bqkv_x = (const float*)d_in[4];
    const float* Wqkv_y = (const float*)d_in[5];
    const float* bqkv_y = (const float*)d_in[6];
    const float* w4x    = (const float*)d_in[7];
    const float* w4y    = (const float*)d_in[8];
    const float* w4xy   = (const float*)d_in[9];
    const float* Wgs    = (const float*)d_in[10];
    const float* bgs    = (const float*)d_in[11];
    const float* Wgc    = (const float*)d_in[12];
    const float* bgc    = (const float*)d_in[13];
    const float* Wp     = (const float*)d_in[14];
    const float* bp     = (const float*)d_in[15];

    // Workspace (f-word offsets; proven layout)
    float* ws = (float*)d_ws;
    bf16*  qkv_x_bf = (bf16*)(ws + 0);           // 6,291,456 bf16
    bf16*  qkv_y_bf = (bf16*)(ws + 3145728);     // 1,572,864 bf16
    bf16*  gated_bf = (bf16*)(ws + 3932160);
    bf16*  cval_bf  = (bf16*)(ws + 5242880);
    bf16*  x2y_bf   = (bf16*)(ws + 12320768);    // 8,388,608 bf16 (written by catt3rv)
    bf16*  x_bf     = x2y_bf;                    //   pre-QKV reuse
    bf16*  y_bf     = (bf16*)(ws + 13369344);    //   pre-QKV reuse
    bf16*  vTx_bf   = (bf16*)(ws + 20709376);    // 2,097,152 bf16
    bf16*  vTy_bf   = (bf16*)(ws + 21757952);    // 524,288 bf16
    float* psum_    = ws + 22020096;             // 131,072 f
    bf16*  qw_bf    = (bf16*)(ws + 26214400);    // (dead slot; reused as sval)
    bf16*  sval_bf  = qw_bf;
    bf16*  WT_x     = (bf16*)(ws + 27262976);    // 786,432 bf16
    bf16*  WT_y     = (bf16*)(ws + 27656192);
    bf16*  WT_gs    = (bf16*)(ws + 28049408);    // 262,144 bf16
    bf16*  WT_gc    = (bf16*)(ws + 28180480);
    bf16*  WT_p    = (bf16*)(ws + 28311552);
    float* rowsum_  = ws + 28491776;             // 32,768 f

    // 0: one prep dispatch
    prep_kernel<<<1856, 256, 0, stream>>>(
        Wqkv_x, Wqkv_y, Wgs, Wgc, Wp, x, y,
        WT_x, WT_y, WT_gs, WT_gc, WT_p, x_bf, y_bf);

    // 1: QKV projections (x + y merged, XCD-swizzled)
    qkv_gemm_kernel<<<960, 256, 0, stream>>>(
        x_bf, y_bf, WT_x, WT_y, bqkv_x, bqkv_y, qkv_x_bf, qkv_y_bf);

    // 2: catt1/catt2 inline + logits + row softmax + V transposes (merged)
    catt3rv_kernel<<<1152, 256, 0, stream>>>(
        qkv_x_bf, qkv_y_bf, w4x, w4y, w4xy, x2y_bf, rowsum_, psum_, vTx_bf, vTy_bf);

    // 3: flash (colfin folded in)
    flash15_kernel<<<dim3(32, 8), 512, 0, stream>>>(
        x2y_bf, rowsum_, psum_, vTx_bf, vTy_bf, qkv_x_bf, x, cval_bf, sval_bf);

    // 4: fused gates (global_load_lds staging)
    gatefuse_kernel<<<dim3(32, 8), 256, 0, stream>>>(
        sval_bf, cval_bf, WT_gs, WT_gc, bgs, bgc, gated_bf);

    // 5: out = gated @ Wp + bp
    gemm_staged_kernel<float><<<dim3(32, 8), 256, 0, stream>>>(
        gated_bf, WT_p, bp, (float*)d_out, C_, C_);
}